// Round 3
// baseline (458.186 us; speedup 1.0000x reference)
//
#include <hip/hip_runtime.h>
#include <cstdint>

// Geometry: B=8, C=512, H=37, W=50, HW=1850, BHW=14800, anchors A=16650, K1=400
#define BHW_ 14800
#define CHW_ 947200   // 512*1850
#define A_   16650
#define OCLS 532800   // cls_pred start
#define OBOX 799200   // boxes start
#define OKEEP 812000  // keep start
#define NSTEP 144     // 16 cc-chunks * 9 khw

typedef unsigned int u32;
typedef unsigned long long u64;
typedef _Float16 f16x8 __attribute__((ext_vector_type(8)));
typedef float f32x4 __attribute__((ext_vector_type(4)));

union U8 { f16x8 v; u32 u[4]; };
union H2U { _Float16 f; unsigned short u; };

__device__ __forceinline__ unsigned int fkey(float f){
  unsigned int u = __float_as_uint(f);
  return (u & 0x80000000u) ? ~u : (u | 0x80000000u);
}

// anchors exactly as numpy: w = (16*s)/sqrt(r), h = (16*s)*sqrt(r), f64 then f32 cast
__device__ __forceinline__ void anchor_corners(int x, int y, int kk,
                                               float& ax1, float& ay1, float& ax2, float& ay2){
  int si = kk % 3, ri = kk / 3;
  double rv = (ri==0) ? 0.5 : ((ri==1) ? 1.0 : 2.0);
  double sr = sqrt(rv);
  double fs = 128.0 * (double)(si+1);
  double h = fs * sr, w = fs / sr;
  double cx = (double)(x*16 + 8), cy = (double)(y*16 + 8);
  ax1 = (float)(cx - w*0.5); ay1 = (float)(cy - h*0.5);
  ax2 = (float)(cx + w*0.5); ay2 = (float)(cy + h*0.5);
}

// --- weight split -> tile-linear f16 chunks.
// Whl chunk index = ((s*4 + otile)*1024 + c), c = (gg*2+hl)*128 + m ; 8 f16 per chunk (k-octet j)
__global__ __launch_bounds__(256) void k_split_w(const float* __restrict__ w, _Float16* __restrict__ Whl){
  int t = blockIdx.x*256 + threadIdx.x;
  if (t >= NSTEP*4*1024) return;
  int c = t & 1023;
  int otile = (t >> 10) & 3;
  int s = t >> 12;
  int m = c & 127, hl = (c >> 7) & 1, gg = c >> 8;
  int o = otile*128 + m;
  int khw = s % 9, cc = s / 9;
  f16x8 out;
  #pragma unroll
  for (int j = 0; j < 8; ++j){
    int ci = cc*32 + gg*8 + j;
    float v = w[(o*512 + ci)*9 + khw];
    _Float16 h = (_Float16)v;
    out[j] = hl ? (_Float16)(v - (float)h) : h;
  }
  *(f16x8*)&Whl[(size_t)t * 8] = out;
}

// --- feature split -> padded NCHW packed u32 (lo<<16 | hi). Fp[b*512+c][39][52]
__global__ __launch_bounds__(256) void k_split_f(const float* __restrict__ feat, u32* __restrict__ Fp){
  int t = blockIdx.x*256 + threadIdx.x;
  if (t >= 8*512*2028) return;
  int xp = t % 52;
  int rest = t / 52;
  int yp = rest % 39;
  int bc = rest / 39;
  float v = 0.f;
  int x = xp - 1, y = yp - 1;
  if ((unsigned)x < 50u && (unsigned)y < 37u)
    v = feat[(size_t)bc*1850 + y*50 + x];
  _Float16 h = (_Float16)v;
  _Float16 l = (_Float16)(v - (float)h);
  H2U hu, lu; hu.f = h; lu.f = l;
  Fp[t] = ((u32)lu.u << 16) | (u32)hu.u;
}

// --- pack head weights [ci][64]: rows 0-17 cls, 18-53 off, 54-63 zero
__global__ __launch_bounds__(256) void k_pack_heads(const float* __restrict__ cw, const float* __restrict__ cb,
                                                    const float* __restrict__ ow, const float* __restrict__ ob,
                                                    float* __restrict__ hwp, float* __restrict__ hb){
  int t = blockIdx.x*256 + threadIdx.x;
  if (t < 64) hb[t] = (t < 18) ? cb[t] : (t < 54 ? ob[t-18] : 0.f);
  if (t >= 512*64) return;
  int r = t & 63, ci = t >> 6;
  hwp[t] = (r < 18) ? cw[r*512 + ci] : (r < 54 ? ow[(r-18)*512 + ci] : 0.f);
}

// --- 3x3 conv, implicit GEMM, f16x2-split MFMA, pre-split inputs.
// BM=128 (o), BN=128 (pos), BK=32; 256 thr = 4 waves (2x2 of 64x64).
// LDS dbuf; A staged via global_load_lds(16B); B via packed-u32 regs + unpack.
__global__ __launch_bounds__(256) void k_conv3_mfma(const u32* __restrict__ Fp,
                                                    const _Float16* __restrict__ Whl,
                                                    const float* __restrict__ mdb,
                                                    float* __restrict__ out0){
  __shared__ _Float16 Abuf[2][1024][8];
  __shared__ _Float16 Bbuf[2][1024][8];

  const int tid = threadIdx.x;
  // bijective XCD swizzle: 464 = 8*58
  int flat = blockIdx.x;
  int xcd = flat & 7, sub = flat >> 3;
  int swz = xcd * 58 + sub;
  int otile = swz / 116;
  int ntile = swz - otile*116;

  // B staging decode (thread -> one n column, 16 k rows)
  const int cpos = tid & 127;
  const int kg = tid >> 7;       // 0..1
  int n = ntile*128 + cpos;
  if (n >= BHW_) n = BHW_ - 1;   // clamp; garbage columns never stored
  int nb = n/1850; int rem = n - nb*1850; int ny = rem/50; int nx = rem - ny*50;
  const u32* bbase = Fp + (size_t)(nb*512 + kg*16)*2028 + (ny+1)*52 + (nx+1);

  u32 R[16];
  auto loadB = [&](int s){
    int cc = s/9, khw = s - cc*9;
    int dy = khw/3 - 1, dx = khw - (khw/3)*3 - 1;
    const u32* src = bbase + (size_t)cc*32*2028 + dy*52 + dx;
    #pragma unroll
    for (int i = 0; i < 16; ++i) R[i] = src[(size_t)i*2028];
  };

  auto writeB = [&](int cur){
    #pragma unroll
    for (int g2 = 0; g2 < 2; ++g2){
      U8 hi, lo;
      #pragma unroll
      for (int p = 0; p < 4; ++p){
        u32 P0 = R[g2*8 + 2*p], P1 = R[g2*8 + 2*p + 1];
        hi.u[p] = (P1 << 16) | (P0 & 0xFFFFu);
        lo.u[p] = (P0 >> 16) | (P1 & 0xFFFF0000u);
      }
      int gg = kg*2 + g2;
      *(f16x8*)&Bbuf[cur][(gg*2 + 0)*128 + cpos][0] = hi.v;
      *(f16x8*)&Bbuf[cur][(gg*2 + 1)*128 + cpos][0] = lo.v;
    }
  };

  auto stageA = [&](int s, int cur){
    const _Float16* g = Whl + ((size_t)(s*4 + otile) * 1024 + tid) * 8;
    _Float16* l = &Abuf[cur][tid][0];
    #pragma unroll
    for (int i = 0; i < 4; ++i)
      __builtin_amdgcn_global_load_lds((const __attribute__((address_space(1))) void*)(g + i*2048),
                                       (__attribute__((address_space(3))) void*)(l + i*2048), 16, 0, 0);
  };

  // compute role
  const int w = tid >> 6, lane = tid & 63;
  const int wm = w >> 1, wn = w & 1;
  const int l15 = lane & 15, l4 = lane >> 4;

  f32x4 acc[4][4] = {};

  // prologue: stage step 0 into buf0
  loadB(0);
  stageA(0, 0);
  writeB(0);                 // compiler waits vmcnt for R (drains A too)
  __syncthreads();

  int cur = 0;
  for (int s = 0; s < NSTEP; ++s){
    if (s < NSTEP-1){
      loadB(s+1);            // issue early; consumed after MFMA phase
      stageA(s+1, cur^1);    // async -> other buffer
      __builtin_amdgcn_sched_barrier(0);
    }

    f16x8 ah[4], al[4], bh[4], bl[4];
    #pragma unroll
    for (int mf = 0; mf < 4; ++mf){
      int m = wm*64 + mf*16 + l15;
      ah[mf] = *(const f16x8*)&Abuf[cur][(l4*2 + 0)*128 + m][0];
      al[mf] = *(const f16x8*)&Abuf[cur][(l4*2 + 1)*128 + m][0];
    }
    #pragma unroll
    for (int nf = 0; nf < 4; ++nf){
      int nn = wn*64 + nf*16 + l15;
      bh[nf] = *(const f16x8*)&Bbuf[cur][(l4*2 + 0)*128 + nn][0];
      bl[nf] = *(const f16x8*)&Bbuf[cur][(l4*2 + 1)*128 + nn][0];
    }
    #pragma unroll
    for (int mf = 0; mf < 4; ++mf)
      #pragma unroll
      for (int nf = 0; nf < 4; ++nf){
        acc[mf][nf] = __builtin_amdgcn_mfma_f32_16x16x32_f16(ah[mf], bh[nf], acc[mf][nf], 0, 0, 0);
        acc[mf][nf] = __builtin_amdgcn_mfma_f32_16x16x32_f16(ah[mf], bl[nf], acc[mf][nf], 0, 0, 0);
        acc[mf][nf] = __builtin_amdgcn_mfma_f32_16x16x32_f16(al[mf], bh[nf], acc[mf][nf], 0, 0, 0);
      }

    if (s < NSTEP-1) writeB(cur^1);
    __syncthreads();
    cur ^= 1;
  }

  // epilogue: D row = l4*4 + r, col = l15 within each 16x16 frag
  #pragma unroll
  for (int nf = 0; nf < 4; ++nf){
    int ng = ntile*128 + wn*64 + nf*16 + l15;
    if (ng >= BHW_) continue;
    int b2 = ng/1850; int rem2 = ng - b2*1850;
    #pragma unroll
    for (int mf = 0; mf < 4; ++mf){
      int o0 = otile*128 + wm*64 + mf*16 + l4*4;
      #pragma unroll
      for (int r = 0; r < 4; ++r){
        out0[(size_t)b2*CHW_ + (size_t)(o0 + r)*1850 + rem2] = acc[mf][nf][r] + mdb[o0 + r];
      }
    }
  }
}

// --- BN stats per channel (double accumulation)
__global__ __launch_bounds__(256) void k_bnstats(const float* __restrict__ out0,
                                                 float* __restrict__ bnm, float* __restrict__ bnr){
  __shared__ double s1[256], s2[256];
  int c = blockIdx.x, tid = threadIdx.x;
  double a = 0.0, b = 0.0;
  for (int i = tid; i < BHW_; i += 256){
    int bb = i / 1850; int r = i - bb*1850;
    float v = out0[bb*CHW_ + c*1850 + r];
    a += (double)v; b += (double)v*(double)v;
  }
  s1[tid] = a; s2[tid] = b; __syncthreads();
  for (int off = 128; off; off >>= 1){
    if (tid < off){ s1[tid] += s1[tid+off]; s2[tid] += s2[tid+off]; }
    __syncthreads();
  }
  if (tid == 0){
    double m = s1[0] / 14800.0;
    double var = s2[0] / 14800.0 - m*m;
    bnm[c] = (float)m;
    bnr[c] = 1.0f / sqrtf((float)var + 1e-5f);
  }
}

// --- head GEMM with fused BN+ReLU on staging and fused score-key emission.
// 64 rows x 14800 pos, K=512; scatters cls/off into d_out transposed layouts.
__global__ __launch_bounds__(256) void k_heads(const float* __restrict__ out0, const float* __restrict__ hwp,
                                               const float* __restrict__ hb, const float* __restrict__ bnm,
                                               const float* __restrict__ bnr, const float* __restrict__ gamma,
                                               const float* __restrict__ beta, float* __restrict__ dout,
                                               u64* __restrict__ keys){
#pragma clang fp contract(off)
  __shared__ float As[16][64];
  __shared__ float Bs[16][64];
  __shared__ int sb[64], sy[64], sx[64];
  int tid = threadIdx.x; int ntile = blockIdx.x;
  if (tid < 64){
    int n = ntile*64 + tid;
    if (n < BHW_){ int b = n/1850; int r = n - b*1850; int y = r/50; sb[tid]=b; sy[tid]=y; sx[tid]=r - y*50; }
    else { sb[tid] = -1; sy[tid] = 0; sx[tid] = 0; }
  }
  __syncthreads();
  float acc[4][4] = {};
  const int tx = tid & 15, ty = tid >> 4;
  const int lci = tid >> 4, lo4 = (tid & 15) * 4;
  for (int ct = 0; ct < 32; ++ct){
    int cib = ct*16;
    float4 av = *(const float4*)(hwp + (cib + lci)*64 + lo4);
    float4 bv; float* bp = (float*)&bv;
    int cig = cib + lci;
    float gm = gamma[cig], mm = bnm[cig], rr = bnr[cig], bt = beta[cig];
    #pragma unroll
    for (int j = 0; j < 4; ++j){
      int nn = lo4 + j; int b = sb[nn];
      float v = 0.f;
      if (b >= 0){
        float x = out0[b*CHW_ + cig*1850 + sy[nn]*50 + sx[nn]];
        float y = gm * (x - mm);
        y = y * rr;
        y = y + bt;
        v = fmaxf(y, 0.f);
      }
      bp[j] = v;
    }
    __syncthreads();
    *(float4*)&As[lci][lo4] = av;
    *(float4*)&Bs[lci][lo4] = bv;
    __syncthreads();
    #pragma unroll
    for (int k = 0; k < 16; ++k){
      float4 a4 = *(const float4*)&As[k][ty*4];
      float4 b4 = *(const float4*)&Bs[k][tx*4];
      const float* ap = (const float*)&a4; const float* bq = (const float*)&b4;
      #pragma unroll
      for (int i = 0; i < 4; ++i)
        #pragma unroll
        for (int j = 0; j < 4; ++j)
          acc[i][j] = fmaf(ap[i], bq[j], acc[i][j]);
    }
  }
  #pragma unroll
  for (int i = 0; i < 4; ++i){
    int r = ty*4 + i;
    if (r >= 54) continue;
    float bias = hb[r];
    #pragma unroll
    for (int j = 0; j < 4; ++j){
      int nl = tx*4 + j;
      int b = sb[nl];
      if (b < 0) continue;
      int pos = sy[nl]*50 + sx[nl];
      float v = acc[i][j] + bias;
      if (r < 18){
        int kk = r >> 1, cc = r & 1;
        dout[OCLS + ((size_t)b*A_ + pos*9 + kk)*2 + cc] = v;
      } else {
        int r2 = r - 18, kk = r2 >> 2, cc = r2 & 3;
        dout[((size_t)b*A_ + pos*9 + kk)*4 + cc] = v;
      }
    }
  }
  // fused score-key: rows (2kk, 2kk+1) always live in the same thread (i even)
  if (ty < 5){
    #pragma unroll
    for (int i = 0; i < 4; i += 2){
      int r = ty*4 + i;
      if (r >= 18) continue;
      int kk = r >> 1;
      float b0 = hb[r], b1 = hb[r+1];
      #pragma unroll
      for (int j = 0; j < 4; ++j){
        int nl = tx*4 + j;
        int b = sb[nl];
        if (b < 0) continue;
        float c0 = acc[i][j] + b0;
        float c1 = acc[i+1][j] + b1;
        float d = c1 - c0;
        float ax1, ay1, ax2, ay2;
        anchor_corners(sx[nl], sy[nl], kk, ax1, ay1, ax2, ay2);
        bool valid = (ax1 >= 0.f) && (ay1 >= 0.f) && (ax2 < 800.f) && (ay2 < 592.f);
        unsigned a = (unsigned)(sy[nl]*50 + sx[nl])*9u + (unsigned)kk;
        u64 key = valid ? (((u64)fkey(d) << 32) | (u64)(~a)) : 0ull;
        keys[(size_t)b*A_ + a] = key;
      }
    }
  }
}

// --- histogram cutoff + candidate compaction (per batch)
__global__ __launch_bounds__(1024) void k_select(const u64* __restrict__ keys,
                                                 u64* __restrict__ cand, unsigned int* __restrict__ ccnt){
  __shared__ unsigned int bins[4096];
  __shared__ unsigned int sp[1024];
  __shared__ unsigned int sbstar;
  __shared__ unsigned int scnt;
  int b = blockIdx.x, tid = threadIdx.x;
  const u64* kb = keys + (size_t)b*A_;
  for (int i = tid; i < 4096; i += 1024) bins[i] = 0u;
  if (tid == 0) scnt = 0u;
  __syncthreads();
  for (int i = tid; i < A_; i += 1024){
    u64 k = kb[i];
    if (k) atomicAdd(&bins[(unsigned int)(k >> 52)], 1u);
  }
  __syncthreads();
  unsigned int p = bins[tid*4] + bins[tid*4+1] + bins[tid*4+2] + bins[tid*4+3];
  sp[tid] = p; __syncthreads();
  for (int off = 1; off < 1024; off <<= 1){
    unsigned int v = sp[tid] + ((tid + off < 1024) ? sp[tid + off] : 0u);
    __syncthreads(); sp[tid] = v; __syncthreads();
  }
  if (sp[tid] >= 400u && (tid == 1023 || sp[tid+1] < 400u)){
    unsigned int base = (tid == 1023) ? 0u : sp[tid+1];
    unsigned int cum = base; int bs = tid*4;
    for (int bb = tid*4 + 3; bb >= tid*4; --bb){
      cum += bins[bb];
      if (cum >= 400u){ bs = bb; break; }
    }
    sbstar = (unsigned int)bs;
  }
  __syncthreads();
  unsigned int bstar = sbstar;
  for (int i = tid; i < A_; i += 1024){
    u64 k = kb[i];
    if (k && (unsigned int)(k >> 52) >= bstar){
      unsigned int pidx = atomicAdd(&scnt, 1u);
      cand[(size_t)b*A_ + pidx] = k;
    }
  }
  __syncthreads();
  if (tid == 0) ccnt[b] = scnt;
}

// --- exact rank-by-counting among candidates -> ordered top-400 keys
__global__ __launch_bounds__(1024) void k_rank(const u64* __restrict__ cand,
                                               const unsigned int* __restrict__ ccnt,
                                               u64* __restrict__ topk){
  __shared__ u64 ch[2048];
  int b = blockIdx.x, tid = threadIdx.x;
  int C = (int)ccnt[b];
  const u64* cb = cand + (size_t)b*A_;
  u64 mk[17]; int mc[17]; int nm = 0;
  for (int i = tid; i < C; i += 1024){ mk[nm] = cb[i]; mc[nm] = 0; ++nm; }
  for (int base = 0; base < C; base += 2048){
    int lim = min(2048, C - base);
    __syncthreads();
    for (int i = tid; i < lim; i += 1024) ch[i] = cb[base + i];
    __syncthreads();
    for (int t = 0; t < nm; ++t){
      u64 my = mk[t]; int cc = 0;
      for (int j = 0; j < lim; ++j) cc += (ch[j] > my) ? 1 : 0;
      mc[t] += cc;
    }
  }
  for (int t = 0; t < nm; ++t)
    if (mc[t] < 400) topk[b*400 + mc[t]] = mk[t];
}

// --- decode boxes (write out) + greedy NMS on truncated boxes -> keep
__global__ __launch_bounds__(512) void k_nms(const u64* __restrict__ topk,
                                             float* __restrict__ dout){
#pragma clang fp contract(off)
  __shared__ float X1[400], Y1[400], X2[400], Y2[400], AR[400];
  __shared__ bool SUP[400];
  int b = blockIdx.x, tid = threadIdx.x;
  if (tid < 400){
    u64 key = topk[b*400 + tid];
    unsigned int a = ~(unsigned int)(key & 0xFFFFFFFFull);
    int pos = a / 9; int kk = a - pos*9;
    int y = pos / 50; int x = pos - y*50;
    float ax1, ay1, ax2, ay2;
    anchor_corners(x, y, (int)kk, ax1, ay1, ax2, ay2);
    float xa = (ax1 + ax2) * 0.5f;
    float ya = (ay1 + ay2) * 0.5f;
    float wa = ax2 - ax1 + 1.0f;
    float ha = ay2 - ay1 + 1.0f;
    const float* t = dout + ((size_t)b*A_ + a)*4;
    float t0 = t[0], t1 = t[1], t2 = t[2], t3 = t[3];
    float xc = t0 * wa + xa;
    float yc = t1 * ha + ya;
    float bw = wa * expf(t2);
    float bh = ha * expf(t3);
    float bx1 = xc - bw*0.5f, by1 = yc - bh*0.5f;
    float bx2 = xc + bw*0.5f, by2 = yc + bh*0.5f;
    float* bo = dout + OBOX + ((size_t)b*400 + tid)*4;
    bo[0] = bx1; bo[1] = by1; bo[2] = bx2; bo[3] = by2;
    float tx1 = truncf(bx1), ty1 = truncf(by1), tx2 = truncf(bx2), ty2 = truncf(by2);
    X1[tid] = tx1; Y1[tid] = ty1; X2[tid] = tx2; Y2[tid] = ty2;
    AR[tid] = (tx2 - tx1 + 1.0f) * (ty2 - ty1 + 1.0f);
    SUP[tid] = false;
  }
  __syncthreads();
  for (int i = 0; i < 399; ++i){
    bool alive = !SUP[i];
    if (alive && tid > i && tid < 400){
      float iw = fminf(X2[i], X2[tid]) - fmaxf(X1[i], X1[tid]) + 1.0f; iw = fmaxf(iw, 0.f);
      float ih = fminf(Y2[i], Y2[tid]) - fmaxf(Y1[i], Y1[tid]) + 1.0f; ih = fmaxf(ih, 0.f);
      float inter = iw * ih;
      float iou = inter / ((AR[i] + AR[tid]) - inter);
      if (iou > 0.6f) SUP[tid] = true;
    }
    __syncthreads();
  }
  if (tid < 400) dout[OKEEP + b*400 + tid] = SUP[tid] ? 0.f : 1.f;
}

extern "C" void kernel_launch(void* const* d_in, const int* in_sizes, int n_in,
                              void* d_out, int out_size, void* d_ws, size_t ws_size,
                              hipStream_t stream){
  const float* feat  = (const float*)d_in[0];
  const float* mdw   = (const float*)d_in[1];
  const float* mdb   = (const float*)d_in[2];
  const float* gamma = (const float*)d_in[3];
  const float* beta  = (const float*)d_in[4];
  const float* clsw  = (const float*)d_in[5];
  const float* clsb  = (const float*)d_in[6];
  const float* offw  = (const float*)d_in[7];
  const float* offb  = (const float*)d_in[8];
  float* dout = (float*)d_out;
  float* ws = (float*)d_ws;

  float* out0 = ws;                                 // 7,577,600 f32
  _Float16* Whl = (_Float16*)(out0 + 7577600);      // 4,718,592 f16 = 2,359,296 f32
  u32* Fp = (u32*)(out0 + 7577600 + 2359296);       // 8,306,688 u32
  float* hwp = (float*)(Fp + 8306688);              // 32,768
  float* hb  = hwp + 32768;                         // 64
  float* bnm = hb + 64;                             // 512
  float* bnr = bnm + 512;                           // 512
  u64* keys = (u64*)(bnr + 512);                    // 133,200 u64
  u64* cand = keys + 133200;                        // 133,200 u64
  u64* topk = cand + 133200;                        // 3,200 u64
  unsigned int* ccnt = (unsigned int*)(topk + 3200);// 8 u32
  // total ws use ~75.3 MB

  k_split_w<<<dim3(2304), 256, 0, stream>>>(mdw, Whl);
  k_split_f<<<dim3(32448), 256, 0, stream>>>(feat, Fp);
  k_pack_heads<<<dim3(128), 256, 0, stream>>>(clsw, clsb, offw, offb, hwp, hb);
  k_conv3_mfma<<<dim3(464), 256, 0, stream>>>(Fp, Whl, mdb, out0);
  k_bnstats<<<dim3(512), 256, 0, stream>>>(out0, bnm, bnr);
  k_heads<<<dim3(232), 256, 0, stream>>>(out0, hwp, hb, bnm, bnr, gamma, beta, dout, keys);
  k_select<<<dim3(8), 1024, 0, stream>>>(keys, cand, ccnt);
  k_rank<<<dim3(8), 1024, 0, stream>>>(cand, ccnt, topk);
  k_nms<<<dim3(8), 512, 0, stream>>>(topk, dout);
}